// Round 4
// baseline (232.150 us; speedup 1.0000x reference)
//
#include <hip/hip_runtime.h>

// Problem: patches [B,N,L] fp32; masked_indices [B,M] int.
// Rows listed in masked_indices are replaced by linspace(row[0], row[L-1], L);
// all other rows are copied.
constexpr int B = 256;
constexpr int N = 1024;
constexpr int L = 128;   // row = 128 floats = 32 float4 = 512 B
constexpr int M = 512;
constexpr int ROWS = B * N;                               // 262144
constexpr long long TOTALQ = (long long)ROWS * (L / 4);   // 8,388,608 float4s

// Native vector type: __builtin_nontemporal_* requires scalar/ext_vector
// pointee — HIP's float4 (HIP_vector_type class) is rejected by the builtin.
typedef float fvec4 __attribute__((ext_vector_type(4)));

// Kernel 1: scatter flags — flags[b*N + idx] = 1 for each (b, m).
// No pre-zeroing: ws is poisoned to 0xAA before every launch, and we test == 1,
// so untouched entries (0xAA, or 0 on a fresh buffer) read as "not flagged".
// Duplicate indices write the same value; no hazard.
// Each thread handles 4 indices via one int4 load; M=512 is divisible by 4 so a
// group of 4 never crosses a batch boundary.
__global__ void __launch_bounds__(256)
flag_kernel(const int* __restrict__ idx, unsigned char* __restrict__ flags) {
    int i = blockIdx.x * blockDim.x + threadIdx.x;
    if (i < (B * M) / 4) {
        int4 v = reinterpret_cast<const int4*>(idx)[i];
        unsigned char* fb = flags + (size_t)(i >> 7) * N;  // batch = (i*4)/512
        fb[v.x] = 1; fb[v.y] = 1; fb[v.z] = 1; fb[v.w] = 1;
    }
}

// Kernel 2: fused copy-or-linspace. One float4 per loop step; 32 lanes per row
// → each wave's load/store is 1 KiB contiguous. Streaming traffic (row data in,
// all of out) is non-temporal so it doesn't churn L2 against the flag table.
// Flagged rows read only row[0] and row[127] (wave-broadcast, cached).
__global__ void __launch_bounds__(256)
main_kernel(const float* __restrict__ in,
            const unsigned char* __restrict__ flags,
            float* __restrict__ out) {
    const long long stride = (long long)gridDim.x * blockDim.x;
    for (long long t = (long long)blockIdx.x * blockDim.x + threadIdx.x;
         t < TOTALQ; t += stride) {
        int row  = (int)(t >> 5);      // global row in [0, B*N)
        int quad = (int)t & 31;        // which float4 within the row
        const float* rowp = in + (size_t)row * L;
        fvec4* outq = reinterpret_cast<fvec4*>(out + (size_t)row * L) + quad;

        if (flags[row] == 1) {         // cached load; flag table is L2-resident
            float s = rowp[0];
            float e = rowp[L - 1];
            float d = e - s;
            float l0 = (float)(quad * 4);
            // match reference: start + (end-start) * (l / (L-1))
            fvec4 v;
            v.x = s + d * ((l0 + 0.0f) * (1.0f / 127.0f));
            v.y = s + d * ((l0 + 1.0f) * (1.0f / 127.0f));
            v.z = s + d * ((l0 + 2.0f) * (1.0f / 127.0f));
            v.w = s + d * ((l0 + 3.0f) * (1.0f / 127.0f));
            __builtin_nontemporal_store(v, outq);
        } else {
            fvec4 v = __builtin_nontemporal_load(
                reinterpret_cast<const fvec4*>(rowp) + quad);
            __builtin_nontemporal_store(v, outq);
        }
    }
}

extern "C" void kernel_launch(void* const* d_in, const int* in_sizes, int n_in,
                              void* d_out, int out_size, void* d_ws, size_t ws_size,
                              hipStream_t stream) {
    const float* patches = (const float*)d_in[0];
    const int* masked    = (const int*)d_in[1];
    float* out           = (float*)d_out;
    unsigned char* flags = (unsigned char*)d_ws;   // B*N bytes = 256 KiB

    {
        int total = (B * M) / 4;            // 32768 threads, 4 indices each
        int block = 256;
        int grid = (total + block - 1) / block;   // 128 blocks
        flag_kernel<<<grid, block, 0, stream>>>(masked, flags);
    }
    {
        // Memory-bound: cap grid at 2048 blocks (8 blocks/CU × 256 CU) and
        // grid-stride; 524288 threads × 16 float4s each.
        int block = 256;
        int grid = 2048;
        main_kernel<<<grid, block, 0, stream>>>(patches, flags, out);
    }
}

// Round 5
// 231.795 us; speedup vs baseline: 1.0015x; 1.0015x over previous
//
#include <hip/hip_runtime.h>

// Problem: patches [B,N,L] fp32; masked_indices [B,M] int.
// Rows listed in masked_indices are replaced by linspace(row[0], row[L-1], L);
// all other rows are copied.
constexpr int B = 256;
constexpr int N = 1024;
constexpr int L = 128;   // row = 128 floats = 512 B = 16 segments of 32 B
constexpr int M = 512;
constexpr int ROWS = B * N;                          // 262144
constexpr int SEGS_PER_ROW = L / 8;                  // 16 threads/row, 32 B each
constexpr long long TOTSEG = (long long)ROWS * SEGS_PER_ROW;  // 4,194,304

// Native vector type: __builtin_nontemporal_* requires scalar/ext_vector
// pointee — HIP's float4 (HIP_vector_type class) is rejected by the builtin.
typedef float fvec4 __attribute__((ext_vector_type(4)));

// Kernel 1: scatter flags — flags[b*N + idx] = 1 for each (b, m).
// No pre-zeroing: ws is poisoned to 0xAA before every launch, and we test == 1,
// so untouched entries (0xAA, or 0 on a fresh buffer) read as "not flagged".
// Duplicate indices write the same value; no hazard.
__global__ void __launch_bounds__(256)
flag_kernel(const int* __restrict__ idx, unsigned char* __restrict__ flags) {
    int i = blockIdx.x * blockDim.x + threadIdx.x;
    if (i < (B * M) / 4) {
        int4 v = reinterpret_cast<const int4*>(idx)[i];
        unsigned char* fb = flags + (size_t)(i >> 7) * N;  // batch = (i*4)/512
        fb[v.x] = 1; fb[v.y] = 1; fb[v.z] = 1; fb[v.w] = 1;
    }
}

// Kernel 2: fused copy-or-linspace. Flat launch, one thread per 32-B segment
// (2 × dwordx4), 16 threads per row. vs the previous 16-iteration grid-stride
// loop: half the flag loads / address calc, 2 independent NT loads in flight
// per thread, no loop overhead. Wave = 4 rows → 2-KiB contiguous accesses.
__global__ void __launch_bounds__(256)
main_kernel(const float* __restrict__ in,
            const unsigned char* __restrict__ flags,
            float* __restrict__ out) {
    long long t = (long long)blockIdx.x * blockDim.x + threadIdx.x;
    int row = (int)(t >> 4);          // global row in [0, B*N)
    int seg = (int)t & 15;            // which 32-B segment within the row
    const float* rowp = in + (size_t)row * L;
    fvec4* outq = reinterpret_cast<fvec4*>(out + (size_t)row * L) + seg * 2;

    if (flags[row] == 1) {            // cached load; flag table is L2-resident
        float s = rowp[0];
        float e = rowp[L - 1];
        float d = e - s;
        float l0 = (float)(seg * 8);
        // match reference: start + (end-start) * (l / (L-1))
        fvec4 v0, v1;
        v0.x = s + d * ((l0 + 0.0f) * (1.0f / 127.0f));
        v0.y = s + d * ((l0 + 1.0f) * (1.0f / 127.0f));
        v0.z = s + d * ((l0 + 2.0f) * (1.0f / 127.0f));
        v0.w = s + d * ((l0 + 3.0f) * (1.0f / 127.0f));
        v1.x = s + d * ((l0 + 4.0f) * (1.0f / 127.0f));
        v1.y = s + d * ((l0 + 5.0f) * (1.0f / 127.0f));
        v1.z = s + d * ((l0 + 6.0f) * (1.0f / 127.0f));
        v1.w = s + d * ((l0 + 7.0f) * (1.0f / 127.0f));
        __builtin_nontemporal_store(v0, outq);
        __builtin_nontemporal_store(v1, outq + 1);
    } else {
        const fvec4* inq = reinterpret_cast<const fvec4*>(rowp) + seg * 2;
        fvec4 v0 = __builtin_nontemporal_load(inq);
        fvec4 v1 = __builtin_nontemporal_load(inq + 1);
        __builtin_nontemporal_store(v0, outq);
        __builtin_nontemporal_store(v1, outq + 1);
    }
}

extern "C" void kernel_launch(void* const* d_in, const int* in_sizes, int n_in,
                              void* d_out, int out_size, void* d_ws, size_t ws_size,
                              hipStream_t stream) {
    const float* patches = (const float*)d_in[0];
    const int* masked    = (const int*)d_in[1];
    float* out           = (float*)d_out;
    unsigned char* flags = (unsigned char*)d_ws;   // B*N bytes = 256 KiB

    {
        int total = (B * M) / 4;            // 32768 threads, 4 indices each
        int block = 256;
        int grid = (total + block - 1) / block;   // 128 blocks
        flag_kernel<<<grid, block, 0, stream>>>(masked, flags);
    }
    {
        int block = 256;
        long long grid = (TOTSEG + block - 1) / block;   // 16384 blocks
        main_kernel<<<(int)grid, block, 0, stream>>>(patches, flags, out);
    }
}